// Round 8
// baseline (280.060 us; speedup 1.0000x reference)
//
#include <hip/hip_runtime.h>
#include <hip/hip_bf16.h>
#include <float.h>

#define H 2048
#define E 64
#define TOPK 8
#define RTOK 16  // tokens per router block
#define TT 8     // tokens per block (fallback fused kernel)
#define NT 512   // threads per block (fallback fused kernel)

typedef __attribute__((ext_vector_type(8))) short bf16x8;
typedef __attribute__((ext_vector_type(4))) float f32x4;
typedef __attribute__((ext_vector_type(4))) unsigned short us4;

__device__ __forceinline__ unsigned short f2bf(float f) {
  unsigned u = __float_as_uint(f);
  u += 0x7fffu + ((u >> 16) & 1u);   // RNE
  return (unsigned short)(u >> 16);
}
__device__ __forceinline__ float bf2f(unsigned short s) {
  return __uint_as_float(((unsigned)s) << 16);
}
__device__ __forceinline__ float wred_max(float v) {
#pragma unroll
  for (int o = 32; o > 0; o >>= 1) v = fmaxf(v, __shfl_xor(v, o));
  return v;
}
__device__ __forceinline__ float wred_sum(float v) {
#pragma unroll
  for (int o = 32; o > 0; o >>= 1) v += __shfl_xor(v, o);
  return v;
}

// Convert router_weight and expert_bias fp32 -> bf16 into workspace (L2-resident).
__global__ __launch_bounds__(256) void cvt_kernel(const float* __restrict__ W,
                                                  const float* __restrict__ eb,
                                                  unsigned short* __restrict__ Wb,
                                                  unsigned short* __restrict__ Bb) {
  int i = (blockIdx.x * 256 + threadIdx.x) * 4;
  const float* src;
  unsigned short* dst;
  int off;
  if (i < E * H) { src = W; dst = Wb; off = i; }
  else           { src = eb; dst = Bb; off = i - E * H; }
  float4 v = *(const float4*)(src + off);
  us4 r;
  r[0] = f2bf(v.x); r[1] = f2bf(v.y); r[2] = f2bf(v.z); r[3] = f2bf(v.w);
  *(us4*)(dst + off) = r;
}

// ---------------- Router: barrier-free reg-staged pipeline (T14) --------------
// R7 post-mortem: every LDS/barrier-staged K-loop runs 1.4-1.9 TB/s; every
// barrier-free reg streamer (combine, fill) runs ~6.7 TB/s. So: R3's verified
// split-K x8 layout (16 tok/block, wave wv owns 256-col K-slice, no barrier in
// the K-loop), with a hand-unrolled 3-buffer register pipeline: ISSUE chunk
// c+2's 6 loads -> counted vmcnt(12) (c+1,c+2 stay in flight, never 0) ->
// sched_barrier(0) (pins loads up / MFMA down; rule 18) -> compute chunk c
// from registers ONLY (no VMEM in compute -> nothing for the compiler to
// drain). All buffer indices compile-time (rule 20).
#define R_ISSUE(P, it)                                         \
  P##x0 = *(const float4*)(xp + (it) * 32);                    \
  P##x1 = *(const float4*)(xp + (it) * 32 + 4);                \
  P##w0 = *(const bf16x8*)(wp0 + (it) * 32);                   \
  P##w1 = *(const bf16x8*)(wp1 + (it) * 32);                   \
  P##w2 = *(const bf16x8*)(wp2 + (it) * 32);                   \
  P##w3 = *(const bf16x8*)(wp3 + (it) * 32);

#define R_WAIT(n)                                              \
  asm volatile("s_waitcnt vmcnt(" #n ")" ::: "memory");        \
  __builtin_amdgcn_sched_barrier(0);

#define R_COMPUTE(P)                                                           \
  {                                                                            \
    bf16x8 av;                                                                 \
    av[0] = (short)f2bf(P##x0.x); av[1] = (short)f2bf(P##x0.y);                \
    av[2] = (short)f2bf(P##x0.z); av[3] = (short)f2bf(P##x0.w);                \
    av[4] = (short)f2bf(P##x1.x); av[5] = (short)f2bf(P##x1.y);                \
    av[6] = (short)f2bf(P##x1.z); av[7] = (short)f2bf(P##x1.w);                \
    acc0 = __builtin_amdgcn_mfma_f32_16x16x32_bf16(av, P##w0, acc0, 0, 0, 0);  \
    acc1 = __builtin_amdgcn_mfma_f32_16x16x32_bf16(av, P##w1, acc1, 0, 0, 0);  \
    acc2 = __builtin_amdgcn_mfma_f32_16x16x32_bf16(av, P##w2, acc2, 0, 0, 0);  \
    acc3 = __builtin_amdgcn_mfma_f32_16x16x32_bf16(av, P##w3, acc3, 0, 0, 0);  \
  }

__global__ __launch_bounds__(512, 4) void router_kernel(
    const float* __restrict__ x, const unsigned short* __restrict__ Wb,
    const float* __restrict__ rb, float* __restrict__ msw_g,
    float* __restrict__ mw_g, int* __restrict__ mi_g) {
  __shared__ float lgs[8][RTOK][E + 1];   // 33.3 KB split-K partials
  const int tid = threadIdx.x;
  const int wv = tid >> 6, lane = tid & 63, quad = lane >> 4, m = lane & 15;
  const int t0 = blockIdx.x * RTOK;
  const int k0 = wv * (H / 8);            // 256-col K-slice; 8 chunks of 32

  f32x4 acc0 = {0.f,0.f,0.f,0.f}, acc1 = {0.f,0.f,0.f,0.f};
  f32x4 acc2 = {0.f,0.f,0.f,0.f}, acc3 = {0.f,0.f,0.f,0.f};
  // A-fragment: lane (quad,m) holds x[t0+m][k0 + it*32 + quad*8 .. +8)
  const float* xp = x + (size_t)(t0 + m) * H + k0 + quad * 8;
  const unsigned short* wp0 = Wb + (size_t)( 0 + m) * H + k0 + quad * 8;
  const unsigned short* wp1 = Wb + (size_t)(16 + m) * H + k0 + quad * 8;
  const unsigned short* wp2 = Wb + (size_t)(32 + m) * H + k0 + quad * 8;
  const unsigned short* wp3 = Wb + (size_t)(48 + m) * H + k0 + quad * 8;

  float4 Ax0, Ax1, Bx0, Bx1, Cx0, Cx1;
  bf16x8 Aw0, Aw1, Aw2, Aw3, Bw0, Bw1, Bw2, Bw3, Cw0, Cw1, Cw2, Cw3;

  // prologue: chunks 0,1 in flight (12 loads)
  R_ISSUE(A, 0)
  R_ISSUE(B, 1)
  // steady state: 18 outstanding after issue; vmcnt(12) retires oldest chunk
  R_ISSUE(C, 2)  R_WAIT(12)  R_COMPUTE(A)
  R_ISSUE(A, 3)  R_WAIT(12)  R_COMPUTE(B)
  R_ISSUE(B, 4)  R_WAIT(12)  R_COMPUTE(C)
  R_ISSUE(C, 5)  R_WAIT(12)  R_COMPUTE(A)
  R_ISSUE(A, 6)  R_WAIT(12)  R_COMPUTE(B)
  R_ISSUE(B, 7)  R_WAIT(12)  R_COMPUTE(C)
                 R_WAIT(6)   R_COMPUTE(A)
                 R_WAIT(0)   R_COMPUTE(B)

  // C/D layout (verified): col = lane&15 (expert-in-group), row = quad*4+r (token)
#pragma unroll
  for (int r = 0; r < 4; ++r) {
    const int row = quad * 4 + r;
    lgs[wv][row][ 0 + m] = acc0[r];
    lgs[wv][row][16 + m] = acc1[r];
    lgs[wv][row][32 + m] = acc2[r];
    lgs[wv][row][48 + m] = acc3[r];
  }
  __syncthreads();

  // Softmax + top-8: wave wv handles tokens 2wv, 2wv+1; lane = expert.
  const float rbl = rb[lane];
#pragma unroll
  for (int tt = 0; tt < 2; ++tt) {
    const int t = wv * 2 + tt;
    float l = rbl;
#pragma unroll
    for (int kq = 0; kq < 8; ++kq) l += lgs[kq][t][lane];
    const float mx = wred_max(l);
    const float p = expf(l - mx);
    const float inv = 1.f / wred_sum(p);
    float sumw = 0.f, lsel = l;
    float mywk = 0.f;
    int myoff = 0;
#pragma unroll
    for (int k = 0; k < TOPK; ++k) {
      const float mk = wred_max(lsel);
      const unsigned long long b = __ballot(lsel == mk);
      const int idx = __ffsll(b) - 1;          // tie -> lowest index (matches top_k)
      const float wk = expf(mk - mx) * inv;
      sumw += wk;
      if (lane == k) { mywk = wk; myoff = idx * H; }
      if (lane == idx) lsel = -FLT_MAX;
    }
    const int tg = t0 + t;
    if (lane == 0) msw_g[tg] = sumw;
    if (lane < TOPK) {
      mw_g[(size_t)tg * TOPK + lane] = mywk;
      mi_g[(size_t)tg * TOPK + lane] = myoff;
    }
  }
}

// ---------------- Combine: barrier-free, LDS-free pure streaming ----------------
// Measured at ~6.7 TB/s HBM (268 MB / 40 us) -- at the achievable roofline.
__global__ __launch_bounds__(256, 4) void combine_kernel(
    const float* __restrict__ x, const unsigned short* __restrict__ Bb,
    const float* __restrict__ msw_g, const float* __restrict__ mw_g,
    const int* __restrict__ mi_g, float* __restrict__ out) {
  const int tid = threadIdx.x;
  const int wv = tid >> 6, lane = tid & 63;
  const int t = blockIdx.x * 4 + wv;
  const float sw = msw_g[t];
  const float4 w0 = *(const float4*)(mw_g + (size_t)t * TOPK);
  const float4 w1 = *(const float4*)(mw_g + (size_t)t * TOPK + 4);
  const int4  e0 = *(const int4*)(mi_g + (size_t)t * TOPK);
  const int4  e1 = *(const int4*)(mi_g + (size_t)t * TOPK + 4);
  const float wks[8] = {w0.x, w0.y, w0.z, w0.w, w1.x, w1.y, w1.z, w1.w};
  const int   ofs[8] = {e0.x, e0.y, e0.z, e0.w, e1.x, e1.y, e1.z, e1.w};
  const float* xr = x + (size_t)t * H;
  float* orow = out + (size_t)t * H;
#pragma unroll
  for (int ch = 0; ch < 4; ++ch) {
    const int c8 = ch * 512 + lane * 8;
    const float4 xa = *(const float4*)(xr + c8);
    const float4 xb = *(const float4*)(xr + c8 + 4);
    float o[8] = {xa.x * sw, xa.y * sw, xa.z * sw, xa.w * sw,
                  xb.x * sw, xb.y * sw, xb.z * sw, xb.w * sw};
#pragma unroll
    for (int k = 0; k < TOPK; ++k) {
      const bf16x8 bv = *(const bf16x8*)(Bb + ofs[k] + c8);
      const float wk = wks[k];
#pragma unroll
      for (int i = 0; i < 8; ++i) o[i] += wk * bf2f((unsigned short)bv[i]);
    }
    *(float4*)(orow + c8)     = make_float4(o[0], o[1], o[2], o[3]);
    *(float4*)(orow + c8 + 4) = make_float4(o[4], o[5], o[6], o[7]);
  }
}

// ---------------- Fallback fused kernel (no-workspace path) ----------------
__global__ __launch_bounds__(NT, 8) void moe_kernel(
    const float* __restrict__ x, const float* __restrict__ W,
    const float* __restrict__ rb, const float* __restrict__ eb,
    float* __restrict__ out) {
  __shared__ unsigned short xl[TT][H + 8];
  __shared__ float lgp[2][TT][E + 1];
  __shared__ float msw[TT];
  __shared__ float mw[TT][TOPK];
  __shared__ int   mi[TT][TOPK];

  const int tid = threadIdx.x;
  const int t0  = blockIdx.x * TT;
  const int wv = tid >> 6, lane = tid & 63, quad = lane >> 4, m = lane & 15;

  {
    const float* row = x + (size_t)(t0 + wv) * H;
#pragma unroll
    for (int i = 0; i < 8; ++i) {
      const int c = (i * 64 + lane) * 4;
      float4 a = *(const float4*)(row + c);
      us4 ra;
      ra[0] = f2bf(a.x); ra[1] = f2bf(a.y); ra[2] = f2bf(a.z); ra[3] = f2bf(a.w);
      *(us4*)&xl[wv][c] = ra;
    }
  }
  __syncthreads();

  {
    const int eg = wv & 3, kh = wv >> 2;
    const int e = eg * 16 + m;
    const int k0 = kh * (H / 2);
    f32x4 acc = {0.f, 0.f, 0.f, 0.f};
    const unsigned short* xp = &xl[m & 7][k0 + quad * 8];
    const float* wpp = W + (size_t)e * H + k0 + quad * 8;
#pragma unroll 4
    for (int it = 0; it < H / 64; ++it) {
      bf16x8 av = *(const bf16x8*)(xp + it * 32);
      float4 p = *(const float4*)(wpp + it * 32);
      float4 q = *(const float4*)(wpp + it * 32 + 4);
      bf16x8 bv;
      bv[0] = (short)f2bf(p.x); bv[1] = (short)f2bf(p.y);
      bv[2] = (short)f2bf(p.z); bv[3] = (short)f2bf(p.w);
      bv[4] = (short)f2bf(q.x); bv[5] = (short)f2bf(q.y);
      bv[6] = (short)f2bf(q.z); bv[7] = (short)f2bf(q.w);
      acc = __builtin_amdgcn_mfma_f32_16x16x32_bf16(av, bv, acc, 0, 0, 0);
    }
#pragma unroll
    for (int r = 0; r < 4; ++r) {
      const int row = quad * 4 + r;
      if (row < TT) lgp[kh][row][eg * 16 + m] = acc[r];
    }
  }
  __syncthreads();

  {
    const int t = wv;
    float l = lgp[0][t][lane] + lgp[1][t][lane] + rb[lane];
    const float mx = wred_max(l);
    const float p = expf(l - mx);
    const float inv = 1.f / wred_sum(p);
    float sumw = 0.f;
    float lsel = l;
#pragma unroll
    for (int k = 0; k < TOPK; ++k) {
      const float mk = wred_max(lsel);
      const unsigned long long b = __ballot(lsel == mk);
      const int idx = __ffsll(b) - 1;
      const float wk = expf(mk - mx) * inv;
      sumw += wk;
      if (lane == 0) { mw[t][k] = wk; mi[t][k] = idx * H; }
      if (lane == idx) lsel = -FLT_MAX;
    }
    if (lane == 0) msw[t] = sumw;
  }
  __syncthreads();

  {
    const int tg = tid >> 8;
    const int c8 = (tid & 255) * 8;
    const float* ebase = eb + c8;
#pragma unroll 1
    for (int tt = 0; tt < TT / 2; ++tt) {
      const int t = tg * (TT / 2) + tt;
      const float sw = msw[t];
      const float4 w0 = *(const float4*)&mw[t][0];
      const float4 w1 = *(const float4*)&mw[t][4];
      const int4  e0 = *(const int4*)&mi[t][0];
      const int4  e1 = *(const int4*)&mi[t][4];
      const float wks[8] = {w0.x, w0.y, w0.z, w0.w, w1.x, w1.y, w1.z, w1.w};
      const int   ofs[8] = {e0.x, e0.y, e0.z, e0.w, e1.x, e1.y, e1.z, e1.w};
      bf16x8 xv = *(const bf16x8*)&xl[t][c8];
      float o[8];
#pragma unroll
      for (int i = 0; i < 8; ++i) o[i] = bf2f((unsigned short)xv[i]) * sw;
#pragma unroll
      for (int k = 0; k < TOPK; ++k) {
        const float wk = wks[k];
        const float* p = ebase + ofs[k];
        float4 p0 = *(const float4*)p;
        float4 p1 = *(const float4*)(p + 4);
        o[0] += wk * p0.x; o[1] += wk * p0.y; o[2] += wk * p0.z; o[3] += wk * p0.w;
        o[4] += wk * p1.x; o[5] += wk * p1.y; o[6] += wk * p1.z; o[7] += wk * p1.w;
      }
      float* op = out + (size_t)(t0 + t) * H + c8;
      *(float4*)op       = make_float4(o[0], o[1], o[2], o[3]);
      *(float4*)(op + 4) = make_float4(o[4], o[5], o[6], o[7]);
    }
  }
}

extern "C" void kernel_launch(void* const* d_in, const int* in_sizes, int n_in,
                              void* d_out, int out_size, void* d_ws, size_t ws_size,
                              hipStream_t stream) {
  const float* x  = (const float*)d_in[0];
  const float* W  = (const float*)d_in[1];
  const float* rb = (const float*)d_in[2];
  const float* eb = (const float*)d_in[3];
  float* out = (float*)d_out;

  const int T = in_sizes[0] / H;     // 16384
  const size_t szW = (size_t)E * H * sizeof(unsigned short);        // 256 KB
  const size_t meta_sz = (size_t)T * 4 + (size_t)T * TOPK * 4 * 2;  // ~1.06 MB
  const size_t need = 2 * szW + meta_sz;

  if (ws_size >= need) {
    unsigned short* Wb = (unsigned short*)d_ws;
    unsigned short* Bb = Wb + (size_t)E * H;
    float* msw_g = (float*)(Bb + (size_t)E * H);
    float* mw_g  = msw_g + T;
    int*   mi_g  = (int*)(mw_g + (size_t)T * TOPK);
    cvt_kernel<<<(2 * E * H) / (256 * 4), 256, 0, stream>>>(W, eb, Wb, Bb);
    router_kernel<<<T / RTOK, 512, 0, stream>>>(x, Wb, rb, msw_g, mw_g, mi_g);
    combine_kernel<<<T / 4, 256, 0, stream>>>(x, Bb, msw_g, mw_g, mi_g, out);
  } else {
    moe_kernel<<<T / TT, NT, 0, stream>>>(x, W, rb, eb, out);
  }
}